// Round 1
// baseline (17317.747 us; speedup 1.0000x reference)
//
#include <hip/hip_runtime.h>
#include <math.h>

#define NB 512
#define NN 256
#define N_ITERS 400
#define KAPPA_F 0.1f

typedef _Float16 half2_t __attribute__((ext_vector_type(2)));
typedef _Float16 half8_t __attribute__((ext_vector_type(8)));

__device__ inline float fdot2f(half2_t a, half2_t b, float c) {
#if __has_builtin(__builtin_amdgcn_fdot2)
  return __builtin_amdgcn_fdot2(a, b, c, false);
#else
  return (float)a.x * (float)b.x + (float)a.y * (float)b.y + c;
#endif
}

// One block = one batch. 1024 threads = 16 waves, 1 block/CU (128 VGPR cap).
// Thread (q = t>>8, r = t&255) owns G1[r][64q..64q+63] in fp32 regs and
// G2[r][64q..64q+63] in 32 packed-half2 regs.
__global__ __launch_bounds__(1024, 4)
void mvo_kernel(const float* __restrict__ mu,
                const float* __restrict__ U,
                const float* __restrict__ A,
                float* __restrict__ out)
{
  __shared__ alignas(16) float As[16 * NN];   // staging tile (16 rows)
  __shared__ float part1s[1024];
  __shared__ float part2s[1024];
  __shared__ alignas(16) float    wsf[NN];    // w fp32
  __shared__ alignas(16) _Float16 whs[NN];    // w fp16 copy
  __shared__ float vsf[NN];
  __shared__ float mus[NN];
  __shared__ float dslot[16];
  __shared__ float slotA[16];
  __shared__ float slotB[16];

  const int t    = threadIdx.x;
  const int b    = blockIdx.x;
  const int lane = t & 63;
  const int wv   = t >> 6;
  const int q    = t >> 8;   // column-chunk index 0..3 (wave-uniform)
  const int r    = t & 255;  // row index (lane-consecutive)

  const float* __restrict__ Ub = U + (size_t)b * NN * NN;
  const float* __restrict__ Ab = A + (size_t)b * NN * NN;

  if (t < NN) mus[t] = mu[b * NN + t];

  float   acc[64];      // fp32 accumulators; ends life as G1 row-chunk
  half2_t g2reg[32];    // G2 row-chunk, packed fp16
  float d1 = 0.f, d2 = 0.f;

  // ---------------- Gram phase: mat 0 -> G2=A^T A, mat 1 -> G1=U^T U -------
  for (int mat = 0; mat < 2; ++mat) {
    const float4* __restrict__ src = (const float4*)(mat == 0 ? Ab : Ub);
    #pragma unroll
    for (int j = 0; j < 64; ++j) acc[j] = 0.f;
    float4 stage = src[t];  // tile 0: rows 0..15, thread t -> float4 #t
    for (int kt = 0; kt < 16; ++kt) {
      __syncthreads();                    // prior readers done
      ((float4*)As)[t] = stage;           // coalesced, stride-1 banks
      __syncthreads();
      if (kt < 15) stage = src[(kt + 1) * 1024 + t];  // prefetch, overlaps compute
      #pragma unroll
      for (int k = 0; k < 16; ++k) {
        float a = As[k * NN + r];         // lane-consecutive: conflict-free
        const float4* rowp = (const float4*)(As + k * NN + 64 * q);
        #pragma unroll
        for (int jj = 0; jj < 16; ++jj) {
          float4 f = rowp[jj];            // wave-broadcast ds_read_b128: free
          acc[4*jj+0] += a * f.x;
          acc[4*jj+1] += a * f.y;
          acc[4*jj+2] += a * f.z;
          acc[4*jj+3] += a * f.w;
        }
      }
    }
    if (mat == 0) {
      if ((r >> 6) == q) d2 = acc[r & 63];        // trace(G2) contribution
      #pragma unroll
      for (int j = 0; j < 32; ++j) {
        half2_t h; h.x = (_Float16)acc[2*j]; h.y = (_Float16)acc[2*j+1];
        g2reg[j] = h;
      }
    } else {
      if ((r >> 6) == q) d1 = acc[r & 63];        // trace(G1) contribution
    }
  }

  // step = 1/(lambd*froU2 + kappa*froA + 1), froU2=tr(G1), froA=sqrt(tr(G2))
  #pragma unroll
  for (int m = 1; m < 64; m <<= 1) {
    d1 += __shfl_xor(d1, m, 64);
    d2 += __shfl_xor(d2, m, 64);
  }
  if (lane == 0) { slotA[wv] = d1; slotB[wv] = d2; }
  if (t < NN) { wsf[t] = 1.0f / 256.0f; whs[t] = (_Float16)(1.0f / 256.0f); }
  __syncthreads();
  float froU2 = 0.f, froA2 = 0.f;
  #pragma unroll
  for (int k = 0; k < 16; ++k) { froU2 += slotA[k]; froA2 += slotB[k]; }
  const float step = 1.0f / (froU2 + KAPPA_F * sqrtf(froA2) + 1.0f);

  // ---------------- 400 PGD iterations ----------------
  for (int it = 0; it < N_ITERS; ++it) {
    // Phase A: partial matvecs from register-resident G chunks
    float a1a = 0.f, a1b = 0.f, a2a = 0.f, a2b = 0.f;
    const float4* w4 = (const float4*)wsf + 16 * q;   // broadcast reads
    #pragma unroll
    for (int jj = 0; jj < 16; jj += 2) {
      float4 f0 = w4[jj];
      float4 f1 = w4[jj + 1];
      a1a += acc[4*jj+0]*f0.x + acc[4*jj+1]*f0.y + acc[4*jj+2]*f0.z + acc[4*jj+3]*f0.w;
      a1b += acc[4*jj+4]*f1.x + acc[4*jj+5]*f1.y + acc[4*jj+6]*f1.z + acc[4*jj+7]*f1.w;
    }
    const half8_t* wh8 = (const half8_t*)whs + 8 * q;
    #pragma unroll
    for (int jj = 0; jj < 8; jj += 2) {
      union { half8_t v; half2_t p[4]; } u0, u1;
      u0.v = wh8[jj]; u1.v = wh8[jj + 1];
      #pragma unroll
      for (int m2 = 0; m2 < 4; ++m2) {
        a2a = fdot2f(g2reg[4*jj + m2],     u0.p[m2], a2a);
        a2b = fdot2f(g2reg[4*jj + 4 + m2], u1.p[m2], a2b);
      }
    }
    float acc1 = a1a + a1b;
    float acc2 = a2a + a2b;
    // dot(w, G2 w) contribution folded into phase A (saves a barrier)
    float dpart = acc2 * wsf[r];
    #pragma unroll
    for (int m = 1; m < 64; m <<= 1) dpart += __shfl_xor(dpart, m, 64);
    part1s[(q << 8) + r] = acc1;
    part2s[(q << 8) + r] = acc2;
    if (lane == 0) dslot[wv] = dpart;
    __syncthreads();

    // Phase B: combine partials, gradient, candidate v (waves 0..3)
    if (t < NN) {
      float g1 = part1s[r] + part1s[256 + r] + part1s[512 + r] + part1s[768 + r];
      float g2 = part2s[r] + part2s[256 + r] + part2s[512 + r] + part2s[768 + r];
      float dot = 0.f;
      #pragma unroll
      for (int k2 = 0; k2 < 16; ++k2) dot += dslot[k2];
      float nrm  = sqrtf(fmaxf(dot, 1e-12f));
      float grad = -mus[r] + g1 + KAPPA_F * g2 / nrm;
      vsf[r] = wsf[r] - step * grad;
    }
    __syncthreads();

    // Phase C: exact simplex projection (Michelot), wave 0 only
    if (wv == 0) {
      float v0 = vsf[lane];
      float v1 = vsf[64 + lane];
      float v2 = vsf[128 + lane];
      float v3 = vsf[192 + lane];
      float s = v0 + v1 + v2 + v3;
      #pragma unroll
      for (int m = 1; m < 64; m <<= 1) s += __shfl_xor(s, m, 64);
      float tau = (s - 1.0f) * (1.0f / 256.0f);
      float cprev = 256.0f;
      for (int ms = 0; ms < 24; ++ms) {
        float s2 = (v0 > tau ? v0 : 0.f) + (v1 > tau ? v1 : 0.f)
                 + (v2 > tau ? v2 : 0.f) + (v3 > tau ? v3 : 0.f);
        float c2 = (v0 > tau ? 1.f : 0.f) + (v1 > tau ? 1.f : 0.f)
                 + (v2 > tau ? 1.f : 0.f) + (v3 > tau ? 1.f : 0.f);
        #pragma unroll
        for (int m = 1; m < 64; m <<= 1) {
          s2 += __shfl_xor(s2, m, 64);
          c2 += __shfl_xor(c2, m, 64);
        }
        if (c2 == cprev) break;      // active set stable -> tau exact (wave-uniform)
        tau = (s2 - 1.0f) / c2;
        cprev = c2;
      }
      float w0 = fmaxf(v0 - tau, 0.f);
      float w1 = fmaxf(v1 - tau, 0.f);
      float w2 = fmaxf(v2 - tau, 0.f);
      float w3 = fmaxf(v3 - tau, 0.f);
      wsf[lane]       = w0; wsf[64 + lane]  = w1;
      wsf[128 + lane] = w2; wsf[192 + lane] = w3;
      whs[lane]       = (_Float16)w0; whs[64 + lane]  = (_Float16)w1;
      whs[128 + lane] = (_Float16)w2; whs[192 + lane] = (_Float16)w3;
    }
    __syncthreads();
  }

  // Final clamp (already >=0) + renormalize + store
  if (wv == 0) {
    float w0 = wsf[lane], w1 = wsf[64 + lane], w2 = wsf[128 + lane], w3 = wsf[192 + lane];
    float s = w0 + w1 + w2 + w3;
    #pragma unroll
    for (int m = 1; m < 64; m <<= 1) s += __shfl_xor(s, m, 64);
    float inv = 1.0f / (s + 1e-12f);
    float* ob = out + b * NN;
    ob[lane]       = w0 * inv;
    ob[64 + lane]  = w1 * inv;
    ob[128 + lane] = w2 * inv;
    ob[192 + lane] = w3 * inv;
  }
}

extern "C" void kernel_launch(void* const* d_in, const int* in_sizes, int n_in,
                              void* d_out, int out_size, void* d_ws, size_t ws_size,
                              hipStream_t stream) {
  const float* mu = (const float*)d_in[0];
  const float* U  = (const float*)d_in[1];
  const float* A  = (const float*)d_in[2];
  float* out = (float*)d_out;
  hipLaunchKernelGGL(mvo_kernel, dim3(NB), dim3(1024), 0, stream, mu, U, A, out);
}

// Round 2
// 16457.269 us; speedup vs baseline: 1.0523x; 1.0523x over previous
//
#include <hip/hip_runtime.h>
#include <math.h>

#define NB 512
#define NN 256
#define N_ITERS 400
#define KAPPA_F 0.1f

typedef _Float16 half2_t __attribute__((ext_vector_type(2)));
typedef _Float16 half8_t __attribute__((ext_vector_type(8)));

__device__ inline float fdot2f(half2_t a, half2_t b, float c) {
#if __has_builtin(__builtin_amdgcn_fdot2)
  return __builtin_amdgcn_fdot2(a, b, c, false);
#else
  return (float)a.x * (float)b.x + (float)a.y * (float)b.y + c;
#endif
}

// One block = one batch. 1024 threads = 16 waves, 1 block/CU (128 VGPR cap).
// Thread (q = t>>8, r = t&255) owns G1[r][64q..64q+63] in fp32 regs and
// G2[r][64q..64q+63] in 32 packed-half2 regs. NO dynamic indexing into the
// per-thread arrays anywhere (that demotes them to scratch — R1 lesson).
__global__ __launch_bounds__(1024, 4)
void mvo_kernel(const float* __restrict__ mu,
                const float* __restrict__ U,
                const float* __restrict__ A,
                float* __restrict__ out)
{
  __shared__ alignas(16) float As[16 * NN];   // staging tile (16 rows)
  __shared__ float part1s[1024];
  __shared__ float part2s[1024];
  __shared__ alignas(16) float    wsf[NN];    // w fp32
  __shared__ alignas(16) _Float16 whs[NN];    // w fp16 copy
  __shared__ float vsf[NN];
  __shared__ float mus[NN];
  __shared__ float dslot[16];
  __shared__ float slotA[16];
  __shared__ float slotB[16];

  const int t    = threadIdx.x;
  const int b    = blockIdx.x;
  const int lane = t & 63;
  const int wv   = t >> 6;
  const int q    = t >> 8;   // column-chunk index 0..3 (wave-uniform)
  const int r    = t & 255;  // row index (lane-consecutive)

  const float* __restrict__ Ub = U + (size_t)b * NN * NN;
  const float* __restrict__ Ab = A + (size_t)b * NN * NN;

  if (t < NN) mus[t] = mu[b * NN + t];

  float   acc[64];      // fp32 accumulators; ends life as G1 row-chunk
  half2_t g2reg[32];    // G2 row-chunk, packed fp16
  float d1 = 0.f, d2 = 0.f;   // Frobenius partial sums (= traces of Grams)

  // ---------------- Gram phase: mat 0 -> G2=A^T A, mat 1 -> G1=U^T U -------
  for (int mat = 0; mat < 2; ++mat) {
    const float4* __restrict__ src = (const float4*)(mat == 0 ? Ab : Ub);
    #pragma unroll
    for (int j = 0; j < 64; ++j) acc[j] = 0.f;
    float fro = 0.f;
    float4 stage = src[t];  // tile 0: rows 0..15, thread t -> float4 #t
    for (int kt = 0; kt < 16; ++kt) {
      __syncthreads();                    // prior readers done
      ((float4*)As)[t] = stage;           // coalesced, stride-1 banks
      // trace(M^T M) = ||M||_F^2: each element loaded exactly once chip-wide
      fro += stage.x*stage.x + stage.y*stage.y + stage.z*stage.z + stage.w*stage.w;
      __syncthreads();
      if (kt < 15) stage = src[(kt + 1) * 1024 + t];  // prefetch, overlaps compute
      #pragma unroll
      for (int k = 0; k < 16; ++k) {
        float a = As[k * NN + r];         // lane-consecutive: conflict-free
        const float4* rowp = (const float4*)(As + k * NN + 64 * q);
        #pragma unroll
        for (int jj = 0; jj < 16; ++jj) {
          float4 f = rowp[jj];            // wave-broadcast ds_read_b128: free
          acc[4*jj+0] += a * f.x;
          acc[4*jj+1] += a * f.y;
          acc[4*jj+2] += a * f.z;
          acc[4*jj+3] += a * f.w;
        }
      }
    }
    if (mat == 0) {
      d2 = fro;                                     // ||A||_F^2 partial
      #pragma unroll
      for (int j = 0; j < 32; ++j) {
        half2_t h; h.x = (_Float16)acc[2*j]; h.y = (_Float16)acc[2*j+1];
        g2reg[j] = h;
      }
    } else {
      d1 = fro;                                     // ||U||_F^2 partial
    }
  }

  // step = 1/(lambd*froU2 + kappa*froA + 1), froU2=||U||_F^2, froA=||A||_F
  #pragma unroll
  for (int m = 1; m < 64; m <<= 1) {
    d1 += __shfl_xor(d1, m, 64);
    d2 += __shfl_xor(d2, m, 64);
  }
  if (lane == 0) { slotA[wv] = d1; slotB[wv] = d2; }
  if (t < NN) { wsf[t] = 1.0f / 256.0f; whs[t] = (_Float16)(1.0f / 256.0f); }
  __syncthreads();
  float froU2 = 0.f, froA2 = 0.f;
  #pragma unroll
  for (int k = 0; k < 16; ++k) { froU2 += slotA[k]; froA2 += slotB[k]; }
  const float step = 1.0f / (froU2 + KAPPA_F * sqrtf(froA2) + 1.0f);

  // ---------------- 400 PGD iterations ----------------
  for (int it = 0; it < N_ITERS; ++it) {
    // Phase A: partial matvecs from register-resident G chunks
    float a1a = 0.f, a1b = 0.f, a2a = 0.f, a2b = 0.f;
    const float4* w4 = (const float4*)wsf + 16 * q;   // wave-broadcast reads
    #pragma unroll
    for (int jj = 0; jj < 16; jj += 2) {
      float4 f0 = w4[jj];
      float4 f1 = w4[jj + 1];
      a1a += acc[4*jj+0]*f0.x + acc[4*jj+1]*f0.y + acc[4*jj+2]*f0.z + acc[4*jj+3]*f0.w;
      a1b += acc[4*jj+4]*f1.x + acc[4*jj+5]*f1.y + acc[4*jj+6]*f1.z + acc[4*jj+7]*f1.w;
    }
    const half8_t* wh8 = (const half8_t*)whs + 8 * q;
    #pragma unroll
    for (int jj = 0; jj < 8; jj += 2) {
      union { half8_t v; half2_t p[4]; } u0, u1;
      u0.v = wh8[jj]; u1.v = wh8[jj + 1];
      #pragma unroll
      for (int m2 = 0; m2 < 4; ++m2) {
        a2a = fdot2f(g2reg[4*jj + m2],     u0.p[m2], a2a);
        a2b = fdot2f(g2reg[4*jj + 4 + m2], u1.p[m2], a2b);
      }
    }
    float acc1 = a1a + a1b;
    float acc2 = a2a + a2b;
    // dot(w, G2 w) contribution folded into phase A (saves a barrier)
    float dpart = acc2 * wsf[r];
    #pragma unroll
    for (int m = 1; m < 64; m <<= 1) dpart += __shfl_xor(dpart, m, 64);
    part1s[(q << 8) + r] = acc1;
    part2s[(q << 8) + r] = acc2;
    if (lane == 0) dslot[wv] = dpart;
    __syncthreads();

    // Phase B: combine partials, gradient, candidate v (waves 0..3)
    if (t < NN) {
      float g1 = part1s[r] + part1s[256 + r] + part1s[512 + r] + part1s[768 + r];
      float g2 = part2s[r] + part2s[256 + r] + part2s[512 + r] + part2s[768 + r];
      float dot = 0.f;
      #pragma unroll
      for (int k2 = 0; k2 < 16; ++k2) dot += dslot[k2];
      float nrm  = sqrtf(fmaxf(dot, 1e-12f));
      float grad = -mus[r] + g1 + KAPPA_F * g2 / nrm;
      vsf[r] = wsf[r] - step * grad;
    }
    __syncthreads();

    // Phase C: exact simplex projection (Michelot), wave 0 only
    if (wv == 0) {
      float v0 = vsf[lane];
      float v1 = vsf[64 + lane];
      float v2 = vsf[128 + lane];
      float v3 = vsf[192 + lane];
      float s = v0 + v1 + v2 + v3;
      #pragma unroll
      for (int m = 1; m < 64; m <<= 1) s += __shfl_xor(s, m, 64);
      float tau = (s - 1.0f) * (1.0f / 256.0f);
      float cprev = 256.0f;
      for (int ms = 0; ms < 24; ++ms) {
        float s2 = (v0 > tau ? v0 : 0.f) + (v1 > tau ? v1 : 0.f)
                 + (v2 > tau ? v2 : 0.f) + (v3 > tau ? v3 : 0.f);
        float c2 = (v0 > tau ? 1.f : 0.f) + (v1 > tau ? 1.f : 0.f)
                 + (v2 > tau ? 1.f : 0.f) + (v3 > tau ? 1.f : 0.f);
        #pragma unroll
        for (int m = 1; m < 64; m <<= 1) {
          s2 += __shfl_xor(s2, m, 64);
          c2 += __shfl_xor(c2, m, 64);
        }
        if (c2 == cprev) break;      // active set stable -> tau exact (wave-uniform)
        tau = (s2 - 1.0f) / c2;
        cprev = c2;
      }
      float w0 = fmaxf(v0 - tau, 0.f);
      float w1 = fmaxf(v1 - tau, 0.f);
      float w2 = fmaxf(v2 - tau, 0.f);
      float w3 = fmaxf(v3 - tau, 0.f);
      wsf[lane]       = w0; wsf[64 + lane]  = w1;
      wsf[128 + lane] = w2; wsf[192 + lane] = w3;
      whs[lane]       = (_Float16)w0; whs[64 + lane]  = (_Float16)w1;
      whs[128 + lane] = (_Float16)w2; whs[192 + lane] = (_Float16)w3;
    }
    __syncthreads();
  }

  // Final clamp (already >=0) + renormalize + store
  if (wv == 0) {
    float w0 = wsf[lane], w1 = wsf[64 + lane], w2 = wsf[128 + lane], w3 = wsf[192 + lane];
    float s = w0 + w1 + w2 + w3;
    #pragma unroll
    for (int m = 1; m < 64; m <<= 1) s += __shfl_xor(s, m, 64);
    float inv = 1.0f / (s + 1e-12f);
    float* ob = out + b * NN;
    ob[lane]       = w0 * inv;
    ob[64 + lane]  = w1 * inv;
    ob[128 + lane] = w2 * inv;
    ob[192 + lane] = w3 * inv;
  }
}

extern "C" void kernel_launch(void* const* d_in, const int* in_sizes, int n_in,
                              void* d_out, int out_size, void* d_ws, size_t ws_size,
                              hipStream_t stream) {
  const float* mu = (const float*)d_in[0];
  const float* U  = (const float*)d_in[1];
  const float* A  = (const float*)d_in[2];
  float* out = (float*)d_out;
  hipLaunchKernelGGL(mvo_kernel, dim3(NB), dim3(1024), 0, stream, mu, U, A, out);
}

// Round 3
// 16415.767 us; speedup vs baseline: 1.0549x; 1.0025x over previous
//
#include <hip/hip_runtime.h>
#include <math.h>

#define NB 512
#define NN 256
#define N_ITERS 400
#define KAPPA_F 0.1f

typedef _Float16 half2_t __attribute__((ext_vector_type(2)));
typedef _Float16 half8_t __attribute__((ext_vector_type(8)));

__device__ inline float fdot2f(half2_t a, half2_t b, float c) {
#if __has_builtin(__builtin_amdgcn_fdot2)
  return __builtin_amdgcn_fdot2(a, b, c, false);
#else
  return (float)a.x * (float)b.x + (float)a.y * (float)b.y + c;
#endif
}

// One block = one batch. 1024 threads = 16 waves.
// amdgpu_waves_per_eu(4,4) pins occupancy at exactly 4 waves/EU (1 block/CU)
// so the RA gets a hard 128-VGPR budget. R2 lesson: __launch_bounds__'s 2nd
// arg is only a MINIMUM — the backend targeted 8 waves/EU (64 VGPRs) and
// spilled the entire 96-reg G1/G2 working set to scratch (42 GB HBM traffic).
// Thread (q = t>>8, r = t&255) owns G1[r][64q..64q+63] in fp32 regs and
// G2[r][64q..64q+63] in 32 packed-half2 regs. No dynamic indexing into
// per-thread arrays anywhere (R1 lesson: that demotes them to scratch).
__global__
__attribute__((amdgpu_flat_work_group_size(1024, 1024)))
__attribute__((amdgpu_waves_per_eu(4, 4)))
void mvo_kernel(const float* __restrict__ mu,
                const float* __restrict__ U,
                const float* __restrict__ A,
                float* __restrict__ out)
{
  __shared__ alignas(16) float As[16 * NN];   // staging tile (16 rows)
  __shared__ float part1s[1024];
  __shared__ float part2s[1024];
  __shared__ alignas(16) float    wsf[NN];    // w fp32
  __shared__ alignas(16) _Float16 whs[NN];    // w fp16 copy
  __shared__ float vsf[NN];
  __shared__ float mus[NN];
  __shared__ float dslot[16];
  __shared__ float slotA[16];
  __shared__ float slotB[16];

  const int t    = threadIdx.x;
  const int b    = blockIdx.x;
  const int lane = t & 63;
  const int wv   = t >> 6;
  const int q    = t >> 8;   // column-chunk index 0..3 (wave-uniform)
  const int r    = t & 255;  // row index (lane-consecutive)

  const float* __restrict__ Ub = U + (size_t)b * NN * NN;
  const float* __restrict__ Ab = A + (size_t)b * NN * NN;

  if (t < NN) mus[t] = mu[b * NN + t];

  float   acc[64];      // fp32 accumulators; ends life as G1 row-chunk
  half2_t g2reg[32];    // G2 row-chunk, packed fp16
  float d1 = 0.f, d2 = 0.f;   // Frobenius partial sums (= traces of Grams)

  // ---------------- Gram phase: mat 0 -> G2=A^T A, mat 1 -> G1=U^T U -------
  for (int mat = 0; mat < 2; ++mat) {
    const float4* __restrict__ src = (const float4*)(mat == 0 ? Ab : Ub);
    #pragma unroll
    for (int j = 0; j < 64; ++j) acc[j] = 0.f;
    float fro = 0.f;
    float4 stage = src[t];  // tile 0: rows 0..15, thread t -> float4 #t
    for (int kt = 0; kt < 16; ++kt) {
      __syncthreads();                    // prior readers done
      ((float4*)As)[t] = stage;           // coalesced, stride-1 banks
      // trace(M^T M) = ||M||_F^2: each element loaded exactly once chip-wide
      fro += stage.x*stage.x + stage.y*stage.y + stage.z*stage.z + stage.w*stage.w;
      __syncthreads();
      if (kt < 15) stage = src[(kt + 1) * 1024 + t];  // prefetch, overlaps compute
      #pragma unroll
      for (int k = 0; k < 16; ++k) {
        float a = As[k * NN + r];         // lane-consecutive: conflict-free
        const float4* rowp = (const float4*)(As + k * NN + 64 * q);
        #pragma unroll
        for (int jj = 0; jj < 16; ++jj) {
          float4 f = rowp[jj];            // wave-broadcast ds_read_b128: free
          acc[4*jj+0] += a * f.x;
          acc[4*jj+1] += a * f.y;
          acc[4*jj+2] += a * f.z;
          acc[4*jj+3] += a * f.w;
        }
      }
    }
    if (mat == 0) {
      d2 = fro;                                     // ||A||_F^2 partial
      #pragma unroll
      for (int j = 0; j < 32; ++j) {
        half2_t h; h.x = (_Float16)acc[2*j]; h.y = (_Float16)acc[2*j+1];
        g2reg[j] = h;
      }
    } else {
      d1 = fro;                                     // ||U||_F^2 partial
    }
  }

  // step = 1/(lambd*froU2 + kappa*froA + 1), froU2=||U||_F^2, froA=||A||_F
  #pragma unroll
  for (int m = 1; m < 64; m <<= 1) {
    d1 += __shfl_xor(d1, m, 64);
    d2 += __shfl_xor(d2, m, 64);
  }
  if (lane == 0) { slotA[wv] = d1; slotB[wv] = d2; }
  if (t < NN) { wsf[t] = 1.0f / 256.0f; whs[t] = (_Float16)(1.0f / 256.0f); }
  __syncthreads();
  float froU2 = 0.f, froA2 = 0.f;
  #pragma unroll
  for (int k = 0; k < 16; ++k) { froU2 += slotA[k]; froA2 += slotB[k]; }
  const float step = 1.0f / (froU2 + KAPPA_F * sqrtf(froA2) + 1.0f);

  // ---------------- 400 PGD iterations ----------------
  for (int it = 0; it < N_ITERS; ++it) {
    // Phase A: partial matvecs from register-resident G chunks
    float a1a = 0.f, a1b = 0.f, a2a = 0.f, a2b = 0.f;
    const float4* w4 = (const float4*)wsf + 16 * q;   // wave-broadcast reads
    #pragma unroll
    for (int jj = 0; jj < 16; jj += 2) {
      float4 f0 = w4[jj];
      float4 f1 = w4[jj + 1];
      a1a += acc[4*jj+0]*f0.x + acc[4*jj+1]*f0.y + acc[4*jj+2]*f0.z + acc[4*jj+3]*f0.w;
      a1b += acc[4*jj+4]*f1.x + acc[4*jj+5]*f1.y + acc[4*jj+6]*f1.z + acc[4*jj+7]*f1.w;
    }
    const half8_t* wh8 = (const half8_t*)whs + 8 * q;
    #pragma unroll
    for (int jj = 0; jj < 8; jj += 2) {
      union { half8_t v; half2_t p[4]; } u0, u1;
      u0.v = wh8[jj]; u1.v = wh8[jj + 1];
      #pragma unroll
      for (int m2 = 0; m2 < 4; ++m2) {
        a2a = fdot2f(g2reg[4*jj + m2],     u0.p[m2], a2a);
        a2b = fdot2f(g2reg[4*jj + 4 + m2], u1.p[m2], a2b);
      }
    }
    float acc1 = a1a + a1b;
    float acc2 = a2a + a2b;
    // dot(w, G2 w) contribution folded into phase A (saves a barrier)
    float dpart = acc2 * wsf[r];
    #pragma unroll
    for (int m = 1; m < 64; m <<= 1) dpart += __shfl_xor(dpart, m, 64);
    part1s[(q << 8) + r] = acc1;
    part2s[(q << 8) + r] = acc2;
    if (lane == 0) dslot[wv] = dpart;
    __syncthreads();

    // Phase B: combine partials, gradient, candidate v (waves 0..3)
    if (t < NN) {
      float g1 = part1s[r] + part1s[256 + r] + part1s[512 + r] + part1s[768 + r];
      float g2 = part2s[r] + part2s[256 + r] + part2s[512 + r] + part2s[768 + r];
      float dot = 0.f;
      #pragma unroll
      for (int k2 = 0; k2 < 16; ++k2) dot += dslot[k2];
      float nrm  = sqrtf(fmaxf(dot, 1e-12f));
      float grad = -mus[r] + g1 + KAPPA_F * g2 / nrm;
      vsf[r] = wsf[r] - step * grad;
    }
    __syncthreads();

    // Phase C: exact simplex projection (Michelot), wave 0 only
    if (wv == 0) {
      float v0 = vsf[lane];
      float v1 = vsf[64 + lane];
      float v2 = vsf[128 + lane];
      float v3 = vsf[192 + lane];
      float s = v0 + v1 + v2 + v3;
      #pragma unroll
      for (int m = 1; m < 64; m <<= 1) s += __shfl_xor(s, m, 64);
      float tau = (s - 1.0f) * (1.0f / 256.0f);
      float cprev = 256.0f;
      for (int ms = 0; ms < 24; ++ms) {
        float s2 = (v0 > tau ? v0 : 0.f) + (v1 > tau ? v1 : 0.f)
                 + (v2 > tau ? v2 : 0.f) + (v3 > tau ? v3 : 0.f);
        float c2 = (v0 > tau ? 1.f : 0.f) + (v1 > tau ? 1.f : 0.f)
                 + (v2 > tau ? 1.f : 0.f) + (v3 > tau ? 1.f : 0.f);
        #pragma unroll
        for (int m = 1; m < 64; m <<= 1) {
          s2 += __shfl_xor(s2, m, 64);
          c2 += __shfl_xor(c2, m, 64);
        }
        if (c2 == cprev) break;      // active set stable -> tau exact (wave-uniform)
        tau = (s2 - 1.0f) / c2;
        cprev = c2;
      }
      float w0 = fmaxf(v0 - tau, 0.f);
      float w1 = fmaxf(v1 - tau, 0.f);
      float w2 = fmaxf(v2 - tau, 0.f);
      float w3 = fmaxf(v3 - tau, 0.f);
      wsf[lane]       = w0; wsf[64 + lane]  = w1;
      wsf[128 + lane] = w2; wsf[192 + lane] = w3;
      whs[lane]       = (_Float16)w0; whs[64 + lane]  = (_Float16)w1;
      whs[128 + lane] = (_Float16)w2; whs[192 + lane] = (_Float16)w3;
    }
    __syncthreads();
  }

  // Final clamp (already >=0) + renormalize + store
  if (wv == 0) {
    float w0 = wsf[lane], w1 = wsf[64 + lane], w2 = wsf[128 + lane], w3 = wsf[192 + lane];
    float s = w0 + w1 + w2 + w3;
    #pragma unroll
    for (int m = 1; m < 64; m <<= 1) s += __shfl_xor(s, m, 64);
    float inv = 1.0f / (s + 1e-12f);
    float* ob = out + b * NN;
    ob[lane]       = w0 * inv;
    ob[64 + lane]  = w1 * inv;
    ob[128 + lane] = w2 * inv;
    ob[192 + lane] = w3 * inv;
  }
}

extern "C" void kernel_launch(void* const* d_in, const int* in_sizes, int n_in,
                              void* d_out, int out_size, void* d_ws, size_t ws_size,
                              hipStream_t stream) {
  const float* mu = (const float*)d_in[0];
  const float* U  = (const float*)d_in[1];
  const float* A  = (const float*)d_in[2];
  float* out = (float*)d_out;
  hipLaunchKernelGGL(mvo_kernel, dim3(NB), dim3(1024), 0, stream, mu, U, A, out);
}

// Round 4
// 4458.783 us; speedup vs baseline: 3.8840x; 3.6817x over previous
//
#include <hip/hip_runtime.h>
#include <math.h>

#define NB 512
#define NN 256
#define N_ITERS 400
#define KAPPA_F 0.1f

typedef _Float16 half2_t __attribute__((ext_vector_type(2)));
typedef _Float16 half8_t __attribute__((ext_vector_type(8)));

__device__ inline float fdot2f(half2_t a, half2_t b, float c) {
#if __has_builtin(__builtin_amdgcn_fdot2)
  return __builtin_amdgcn_fdot2(a, b, c, false);
#else
  return (float)a.x * (float)b.x + (float)a.y * (float)b.y + c;
#endif
}

// One block = one batch. 1024 threads = 16 waves, 4 waves/EU, 1 block/CU.
//
// R1-R3 lesson chain: per-thread ARRAYS (acc[64], g2reg[32]) were demoted to
// scratch by the middle-end (SROA runs before unrolling -> sees loop-variant
// indices -> alloca survives -> AMDGPUPromoteAlloca declines at this size),
// producing 42 GB of scratch traffic regardless of occupancy attributes.
// Fix: NAMED vector registers only (c0..c15 float4, g00..g73 half2), all
// accesses macro-generated. No local array, no union => no alloca possible.
// Thread (q=t>>8, r=t&255) owns G1[r][64q..64q+63] (c regs, fp32) and
// G2[r][64q..64q+63] (g regs, packed fp16, consumed via v_dot2_f32_f16).

#define ZERO4(J) c##J.x = 0.f; c##J.y = 0.f; c##J.z = 0.f; c##J.w = 0.f;
#define ZERO_ALL() \
  ZERO4(0) ZERO4(1) ZERO4(2) ZERO4(3) ZERO4(4) ZERO4(5) ZERO4(6) ZERO4(7) \
  ZERO4(8) ZERO4(9) ZERO4(10) ZERO4(11) ZERO4(12) ZERO4(13) ZERO4(14) ZERO4(15)

#define GACC(J) { float4 f = rowp4[J]; \
  c##J.x = fmaf(a, f.x, c##J.x); c##J.y = fmaf(a, f.y, c##J.y); \
  c##J.z = fmaf(a, f.z, c##J.z); c##J.w = fmaf(a, f.w, c##J.w); }

// Gram accumulate: c += (SRC^T SRC)[r][64q..64q+63], plus fro += ||tile||^2
#define GRAM(SRC) do { \
  const float4* __restrict__ src4 = (const float4*)(SRC); \
  ZERO_ALL(); \
  fro = 0.f; \
  float4 stage = src4[t]; \
  for (int kt = 0; kt < 16; ++kt) { \
    __syncthreads(); \
    ((float4*)As)[t] = stage; \
    fro += stage.x*stage.x + stage.y*stage.y + stage.z*stage.z + stage.w*stage.w; \
    __syncthreads(); \
    if (kt < 15) stage = src4[(kt + 1) * 1024 + t]; \
    for (int k = 0; k < 16; ++k) { \
      float a = As[k * NN + r]; \
      const float4* rowp4 = (const float4*)(As + k * NN + 64 * q); \
      GACC(0) GACC(1) GACC(2) GACC(3) GACC(4) GACC(5) GACC(6) GACC(7) \
      GACC(8) GACC(9) GACC(10) GACC(11) GACC(12) GACC(13) GACC(14) GACC(15) \
    } \
  } \
} while (0)

// Convert c(CA),c(CB) fp32 -> 4 named half2 of group G (cols 8G..8G+7)
#define CVT(G, CA, CB) { half2_t h; \
  h.x = (_Float16)c##CA.x; h.y = (_Float16)c##CA.y; g##G##0 = h; \
  h.x = (_Float16)c##CA.z; h.y = (_Float16)c##CA.w; g##G##1 = h; \
  h.x = (_Float16)c##CB.x; h.y = (_Float16)c##CB.y; g##G##2 = h; \
  h.x = (_Float16)c##CB.z; h.y = (_Float16)c##CB.w; g##G##3 = h; }

#define G1STEP(J) { float4 f = w4[J]; \
  a1 = fmaf(c##J.x, f.x, fmaf(c##J.y, f.y, fmaf(c##J.z, f.z, fmaf(c##J.w, f.w, a1)))); }

#define G2STEP(J) { half8_t u = wh8[J]; \
  a2 = fdot2f(g##J##0, __builtin_shufflevector(u, u, 0, 1), a2); \
  a2 = fdot2f(g##J##1, __builtin_shufflevector(u, u, 2, 3), a2); \
  a2 = fdot2f(g##J##2, __builtin_shufflevector(u, u, 4, 5), a2); \
  a2 = fdot2f(g##J##3, __builtin_shufflevector(u, u, 6, 7), a2); }

__global__
__attribute__((amdgpu_flat_work_group_size(1024, 1024)))
__attribute__((amdgpu_waves_per_eu(4, 4)))
void mvo_kernel(const float* __restrict__ mu,
                const float* __restrict__ U,
                const float* __restrict__ A,
                float* __restrict__ out)
{
  __shared__ alignas(16) float As[16 * NN];   // staging tile (16 rows)
  __shared__ float part1s[1024];
  __shared__ float part2s[1024];
  __shared__ alignas(16) float    wsf[NN];    // w fp32
  __shared__ alignas(16) _Float16 whs[NN];    // w fp16 copy
  __shared__ float vsf[NN];
  __shared__ float mus[NN];
  __shared__ float dslot[16];
  __shared__ float slotA[16];
  __shared__ float slotB[16];

  const int t    = threadIdx.x;
  const int b    = blockIdx.x;
  const int lane = t & 63;
  const int wv   = t >> 6;
  const int q    = t >> 8;   // column-chunk index 0..3 (wave-uniform)
  const int r    = t & 255;  // row index (lane-consecutive)

  const float* __restrict__ Ub = U + (size_t)b * NN * NN;
  const float* __restrict__ Ab = A + (size_t)b * NN * NN;

  if (t < NN) mus[t] = mu[b * NN + t];

  // Named register state — G1 row-chunk (fp32) and G2 row-chunk (fp16 pairs)
  float4 c0, c1, c2, c3, c4, c5, c6, c7, c8, c9, c10, c11, c12, c13, c14, c15;
  half2_t g00, g01, g02, g03, g10, g11, g12, g13, g20, g21, g22, g23,
          g30, g31, g32, g33, g40, g41, g42, g43, g50, g51, g52, g53,
          g60, g61, g62, g63, g70, g71, g72, g73;
  float fro = 0.f;
  float d1, d2;

  // ---- Gram phase: A first (-> G2, converted to fp16), then U (-> G1) ----
  GRAM(Ab);
  d2 = fro;                               // ||A||_F^2 partial (= tr(G2))
  CVT(0, 0, 1) CVT(1, 2, 3) CVT(2, 4, 5) CVT(3, 6, 7)
  CVT(4, 8, 9) CVT(5, 10, 11) CVT(6, 12, 13) CVT(7, 14, 15)
  GRAM(Ub);
  d1 = fro;                               // ||U||_F^2 partial (= tr(G1))

  // step = 1/(lambd*froU2 + kappa*froA + 1)
  #pragma unroll
  for (int m = 1; m < 64; m <<= 1) {
    d1 += __shfl_xor(d1, m, 64);
    d2 += __shfl_xor(d2, m, 64);
  }
  if (lane == 0) { slotA[wv] = d1; slotB[wv] = d2; }
  if (t < NN) { wsf[t] = 1.0f / 256.0f; whs[t] = (_Float16)(1.0f / 256.0f); }
  __syncthreads();
  float froU2 = 0.f, froA2 = 0.f;
  #pragma unroll
  for (int k = 0; k < 16; ++k) { froU2 += slotA[k]; froA2 += slotB[k]; }
  const float step = 1.0f / (froU2 + KAPPA_F * sqrtf(froA2) + 1.0f);

  // ---------------- 400 PGD iterations ----------------
  for (int it = 0; it < N_ITERS; ++it) {
    // Phase A: partial matvecs from register-resident G chunks
    float a1 = 0.f, a2 = 0.f;
    const float4* w4 = (const float4*)wsf + 16 * q;      // wave-broadcast
    G1STEP(0) G1STEP(1) G1STEP(2) G1STEP(3) G1STEP(4) G1STEP(5) G1STEP(6) G1STEP(7)
    G1STEP(8) G1STEP(9) G1STEP(10) G1STEP(11) G1STEP(12) G1STEP(13) G1STEP(14) G1STEP(15)
    const half8_t* wh8 = (const half8_t*)whs + 8 * q;    // wave-broadcast
    G2STEP(0) G2STEP(1) G2STEP(2) G2STEP(3) G2STEP(4) G2STEP(5) G2STEP(6) G2STEP(7)

    // dot(w, G2 w) contribution folded into phase A (saves a barrier)
    float dpart = a2 * wsf[r];
    #pragma unroll
    for (int m = 1; m < 64; m <<= 1) dpart += __shfl_xor(dpart, m, 64);
    part1s[(q << 8) + r] = a1;
    part2s[(q << 8) + r] = a2;
    if (lane == 0) dslot[wv] = dpart;
    __syncthreads();

    // Phase B: combine partials, gradient, candidate v (waves 0..3)
    if (t < NN) {
      float g1 = part1s[r] + part1s[256 + r] + part1s[512 + r] + part1s[768 + r];
      float g2 = part2s[r] + part2s[256 + r] + part2s[512 + r] + part2s[768 + r];
      float dot = 0.f;
      #pragma unroll
      for (int k2 = 0; k2 < 16; ++k2) dot += dslot[k2];
      float nrm  = sqrtf(fmaxf(dot, 1e-12f));
      float grad = -mus[r] + g1 + KAPPA_F * g2 / nrm;
      vsf[r] = wsf[r] - step * grad;
    }
    __syncthreads();

    // Phase C: exact simplex projection (Michelot), wave 0 only
    if (wv == 0) {
      float v0 = vsf[lane];
      float v1 = vsf[64 + lane];
      float v2 = vsf[128 + lane];
      float v3 = vsf[192 + lane];
      float s = v0 + v1 + v2 + v3;
      #pragma unroll
      for (int m = 1; m < 64; m <<= 1) s += __shfl_xor(s, m, 64);
      float tau = (s - 1.0f) * (1.0f / 256.0f);
      float cprev = 256.0f;
      for (int ms = 0; ms < 24; ++ms) {
        float s2 = (v0 > tau ? v0 : 0.f) + (v1 > tau ? v1 : 0.f)
                 + (v2 > tau ? v2 : 0.f) + (v3 > tau ? v3 : 0.f);
        float c2 = (v0 > tau ? 1.f : 0.f) + (v1 > tau ? 1.f : 0.f)
                 + (v2 > tau ? 1.f : 0.f) + (v3 > tau ? 1.f : 0.f);
        #pragma unroll
        for (int m = 1; m < 64; m <<= 1) {
          s2 += __shfl_xor(s2, m, 64);
          c2 += __shfl_xor(c2, m, 64);
        }
        if (c2 == cprev) break;   // active set stable -> tau exact (wave-uniform)
        tau = (s2 - 1.0f) / c2;
        cprev = c2;
      }
      float w0 = fmaxf(v0 - tau, 0.f);
      float w1 = fmaxf(v1 - tau, 0.f);
      float w2 = fmaxf(v2 - tau, 0.f);
      float w3 = fmaxf(v3 - tau, 0.f);
      wsf[lane]       = w0; wsf[64 + lane]  = w1;
      wsf[128 + lane] = w2; wsf[192 + lane] = w3;
      whs[lane]       = (_Float16)w0; whs[64 + lane]  = (_Float16)w1;
      whs[128 + lane] = (_Float16)w2; whs[192 + lane] = (_Float16)w3;
    }
    __syncthreads();
  }

  // Final clamp (already >=0) + renormalize + store
  if (wv == 0) {
    float w0 = wsf[lane], w1 = wsf[64 + lane], w2 = wsf[128 + lane], w3 = wsf[192 + lane];
    float s = w0 + w1 + w2 + w3;
    #pragma unroll
    for (int m = 1; m < 64; m <<= 1) s += __shfl_xor(s, m, 64);
    float inv = 1.0f / (s + 1e-12f);
    float* ob = out + b * NN;
    ob[lane]       = w0 * inv;
    ob[64 + lane]  = w1 * inv;
    ob[128 + lane] = w2 * inv;
    ob[192 + lane] = w3 * inv;
  }
}

extern "C" void kernel_launch(void* const* d_in, const int* in_sizes, int n_in,
                              void* d_out, int out_size, void* d_ws, size_t ws_size,
                              hipStream_t stream) {
  const float* mu = (const float*)d_in[0];
  const float* U  = (const float*)d_in[1];
  const float* A  = (const float*)d_in[2];
  float* out = (float*)d_out;
  hipLaunchKernelGGL(mvo_kernel, dim3(NB), dim3(1024), 0, stream, mu, U, A, out);
}